// Round 5
// baseline (425.497 us; speedup 1.0000x reference)
//
#include <hip/hip_runtime.h>
#include <cstddef>
#include <cstdint>

#define B_ 16
#define N_ 1024
#define CIN_ 256
#define MID_ 512
#define OUT_ 256

typedef __attribute__((ext_vector_type(8))) short short8v;
typedef __attribute__((ext_vector_type(4))) float f32x4;
typedef unsigned long long ull;

__device__ __forceinline__ float sigf(float z){ return 1.f/(1.f+expf(-z)); }
__device__ __forceinline__ ushort f2bf(float f){
  uint32_t u=__float_as_uint(f);
  uint32_t r=(u + 0x7fffu + ((u>>16)&1u))>>16;
  return (ushort)r;
}
__device__ __forceinline__ float bf2f(ushort u){ return __uint_as_float(((uint32_t)u)<<16); }

__device__ __forceinline__ void async16(void* lds, const void* g){
  __builtin_amdgcn_global_load_lds(
      (const __attribute__((address_space(1))) uint32_t*)g,
      (__attribute__((address_space(3))) uint32_t*)lds,
      16, 0, 0);
}

// col bit for column j out of the 16-word mask (j = 4*(wid*64+lane)+k encoding)
__device__ __forceinline__ int colbit(const ull* __restrict__ cm, int j){
  return (int)((cm[((j>>8)<<2) | (j&3)] >> ((j>>2)&63)) & 1ull);
}

// ---------- fused: lj/li dot products + bf16 casts of x and gt ----------
__global__ __launch_bounds__(256) void k_pc(const float* __restrict__ x,
    const float* __restrict__ gt, const float* __restrict__ Watt,
    float* __restrict__ lj, float* __restrict__ li,
    ushort* __restrict__ xb, ushort* __restrict__ gtb)
{
  int bid=blockIdx.x, wid=threadIdx.x>>6, lane=threadIdx.x&63;
  if(bid < 4096){
    int row = bid*4 + wid;
    float4 xv = ((const float4*)(x + (size_t)row*CIN_))[lane];
    ((ushort4*)(xb + (size_t)row*CIN_))[lane] =
        make_ushort4(f2bf(xv.x), f2bf(xv.y), f2bf(xv.z), f2bf(xv.w));
    float4 q = ((const float4*)Watt)[lane];
    float4 w = ((const float4*)(Watt + CIN_))[lane];
    float aq = xv.x*q.x+xv.y*q.y+xv.z*q.z+xv.w*q.w;
    float ak = xv.x*w.x+xv.y*w.y+xv.z*w.z+xv.w*w.w;
    #pragma unroll
    for(int off=32; off; off>>=1){ aq += __shfl_xor(aq,off); ak += __shfl_xor(ak,off); }
    if(lane==0){ lj[row]=aq; li[row]=ak; }
  } else {
    int row = (bid-4096)*4 + wid;
    float4 v = ((const float4*)(gt + (size_t)row*CIN_))[lane];
    ((ushort4*)(gtb + (size_t)row*CIN_))[lane] =
        make_ushort4(f2bf(v.x), f2bf(v.y), f2bf(v.z), f2bf(v.w));
  }
}

// ---------- fused weight prep: W1b, W2b, WgTb ----------
__global__ __launch_bounds__(256) void k_wcast(const float* __restrict__ W1,
    const float* __restrict__ W2, const float* __restrict__ Wg,
    ushort* __restrict__ W1b, ushort* __restrict__ W2b, ushort* __restrict__ WgTb)
{
  int bid=blockIdx.x, t=threadIdx.x;
  if(bid<128){ int i=bid*256+t; W1b[i]=f2bf(W1[i]); }
  else if(bid<256){ int i=(bid-128)*256+t; W2b[i]=f2bf(W2[i]); }
  else { int idx=(bid-256)*256+t; int o=idx>>8, c=idx&255; WgTb[idx]=f2bf(Wg[(size_t)c*OUT_+o]); }
}

// ---------- fused: At0 (no col) + per-row membership bitmask ----------
__global__ __launch_bounds__(256) void k_colat(
    const float* __restrict__ m1, const float* __restrict__ m2,
    const float* __restrict__ sc, const float* __restrict__ lj,
    const float* __restrict__ li, const float* __restrict__ batt,
    ushort* __restrict__ Atb, ull* __restrict__ blockmask)
{
  int row = blockIdx.x; int b = row >> 10; int i = row & 1023;
  int t = threadIdx.x, lane = t&63, wid = t>>6;
  size_t base = (size_t)row*N_ + 4*t;
  float4 m1v = *(const float4*)(m1 + base);
  float4 m2v = *(const float4*)(m2 + base);
  float4 scv = *(const float4*)(sc + (b<<10) + 4*t);
  float4 ljv = *(const float4*)(lj + (b<<10) + 4*t);
  float lir = li[row], ba = batt[0];
  float fi = (sc[(b<<10)+i]==0.f)?1.f:0.f;
  float mr1[4] = {m1v.x*scv.x, m1v.y*scv.y, m1v.z*scv.z, m1v.w*scv.w};
  float mr2[4] = {m2v.x*scv.x, m2v.y*scv.y, m2v.z*scv.z, m2v.w*scv.w};
  float ljr[4] = {ljv.x,ljv.y,ljv.z,ljv.w};
  // At0 = (v*(mr1+mr2) + f*diag)/512  (col NOT applied here)
  ushort o[4];
  #pragma unroll
  for(int k=0;k<4;++k){
    float v = sigf(ljr[k]+lir+ba);
    float val = v*(mr1[k]+mr2[k]);
    if(4*t+k==i) val += fi;
    o[k] = f2bf(val*(1.f/512.f));
  }
  *(ushort4*)(Atb+base) = make_ushort4(o[0],o[1],o[2],o[3]);
  // zero ballots (per wave, per k)
  ull zb1m0=__ballot(mr1[0]==0.f), zb1m1=__ballot(mr1[1]==0.f),
      zb1m2=__ballot(mr1[2]==0.f), zb1m3=__ballot(mr1[3]==0.f);
  ull zb2m0=__ballot(mr2[0]==0.f), zb2m1=__ballot(mr2[1]==0.f),
      zb2m2=__ballot(mr2[2]==0.f), zb2m3=__ballot(mr2[3]==0.f);
  int wz1 = __popcll(zb1m0)+__popcll(zb1m1)+__popcll(zb1m2)+__popcll(zb1m3);
  int wz2 = __popcll(zb2m0)+__popcll(zb2m1)+__popcll(zb2m2)+__popcll(zb2m3);
  __shared__ int wz[8];
  if(lane==0){ wz[wid]=wz1; wz[4+wid]=wz2; }
  __syncthreads();
  int pre1=0, pre2=0, Z1=0, Z2=0;
  #pragma unroll
  for(int w2=0;w2<4;++w2){
    Z1 += wz[w2]; Z2 += wz[4+w2];
    if(w2<wid){ pre1 += wz[w2]; pre2 += wz[4+w2]; }
  }
  ull lt = (1ull<<lane)-1ull;
  int r1 = pre1 + __popcll(zb1m0&lt)+__popcll(zb1m1&lt)+__popcll(zb1m2&lt)+__popcll(zb1m3&lt);
  int r2 = pre2 + __popcll(zb2m0&lt)+__popcll(zb2m1&lt)+__popcll(zb2m2&lt)+__popcll(zb2m3&lt);
  int P1 = 1024-Z1, P2 = 1024-Z2;
  bool rare = (P1>128)||(P2>256)||(Z1<128)||(Z2<128);
  bool q0,q1,q2,q3;
  if(!rare){
    int zb1=r1, zb2=r2;
    q0 = (mr1[0]!=0.f)||(zb1<128)||(mr2[0]!=0.f)||(zb2<128)||(P2+zb2<256);
    zb1 += (int)((zb1m0>>lane)&1ull); zb2 += (int)((zb2m0>>lane)&1ull);
    q1 = (mr1[1]!=0.f)||(zb1<128)||(mr2[1]!=0.f)||(zb2<128)||(P2+zb2<256);
    zb1 += (int)((zb1m1>>lane)&1ull); zb2 += (int)((zb2m1>>lane)&1ull);
    q2 = (mr1[2]!=0.f)||(zb1<128)||(mr2[2]!=0.f)||(zb2<128)||(P2+zb2<256);
    zb1 += (int)((zb1m2>>lane)&1ull); zb2 += (int)((zb2m2>>lane)&1ull);
    q3 = (mr1[3]!=0.f)||(zb1<128)||(mr2[3]!=0.f)||(zb2<128)||(P2+zb2<256);
  } else {
    // exact rank fallback (statistically never taken); recompute from global
    const float* m1r = m1 + (size_t)row*N_;
    const float* m2r = m2 + (size_t)row*N_;
    const float* scr = sc + (b<<10);
    const float* ljp = lj + (b<<10);
    float a1v[4], a2v[4];
    #pragma unroll
    for(int k=0;k<4;++k){
      float v = sigf(ljp[4*t+k]+lir+ba);
      a1v[k]=mr1[k]*v; a2v[k]=mr2[k]*v;
    }
    int c1[4]={0,0,0,0}, c1m[4]={0,0,0,0}, c2[4]={0,0,0,0}, c2m[4]={0,0,0,0};
    for(int jp=0;jp<N_;++jp){
      float vv = sigf(ljp[jp]+lir+ba);
      float p1 = m1r[jp]*scr[jp]*vv, p2 = m2r[jp]*scr[jp]*vv;
      #pragma unroll
      for(int k=0;k<4;++k){
        bool lo = jp < 4*t+k;
        c1[k] += (p1>a1v[k])||((p1==a1v[k])&&lo);
        c1m[k]+= (p1<a1v[k])||((p1==a1v[k])&&lo);
        c2[k] += (p2>a2v[k])||((p2==a2v[k])&&lo);
        c2m[k]+= (p2<a2v[k])||((p2==a2v[k])&&lo);
      }
    }
    q0 = (c1[0]<128||c1m[0]<128||c2[0]<256||c2m[0]<128);
    q1 = (c1[1]<128||c1m[1]<128||c2[1]<256||c2m[1]<128);
    q2 = (c1[2]<128||c1m[2]<128||c2[2]<256||c2m[2]<128);
    q3 = (c1[3]<128||c1m[3]<128||c2[3]<256||c2m[3]<128);
  }
  ull bq0=__ballot(q0), bq1=__ballot(q1), bq2=__ballot(q2), bq3=__ballot(q3);
  if(lane<4){
    ull v = (lane==0)?bq0 : (lane==1)?bq1 : (lane==2)?bq2 : bq3;
    blockmask[(size_t)(wid*4+lane)*16384 + row] = v;
  }
}

// ---------- OR-reduce blockmask -> colmask64 (16 words) ----------
__global__ __launch_bounds__(256) void k_colred(const ull* __restrict__ blockmask,
    ull* __restrict__ colmask64)
{
  int w = blockIdx.x;
  const ull* p = blockmask + (size_t)w*16384;
  ull acc = 0;
  for(int r=threadIdx.x; r<16384; r+=256) acc |= p[r];
  #pragma unroll
  for(int off=32; off; off>>=1) acc |= __shfl_xor(acc, off);
  __shared__ ull sm[4];
  int lane=threadIdx.x&63, wid=threadIdx.x>>6;
  if(lane==0) sm[wid]=acc;
  __syncthreads();
  if(threadIdx.x==0) colmask64[w] = sm[0]|sm[1]|sm[2]|sm[3];
}

// ---------- bf16 MFMA NT GEMM: C[i][m]=sum_k A[i][k]*B[m][k] ----------
// Cb: bf16 main out (optionally column-scaled by colmask); CbT: transposed bf16 copy;
// corrT: exact diag correction  v += f(row)*(1-col(row))*(1/512)*corrT[row][col]
template<int BM,int BN,int WR,int WC,int BK>
__global__ __launch_bounds__(256) void mgemm(
    const ushort* __restrict__ A, int lda, long long sAb, long long sAg,
    const ushort* __restrict__ Bp, int ldb, long long sBb, long long sBg,
    float* __restrict__ C, ushort* __restrict__ Cb, int ldc, long long sCb, long long sCg,
    ushort* __restrict__ CbT, long long sTb, long long sTg, int ldt,
    const ull* __restrict__ colmask, int scaleCb,
    const ushort* __restrict__ corrT, long long sQb, int ldq, const float* __restrict__ scp,
    int K, int nG,
    const float* __restrict__ biasM, int biasMG,
    const float* __restrict__ biasN, int relu)
{
  static_assert(WR*WC==4 && BM==WR*64 && BN==WC*64, "tile");
  __shared__ __align__(16) ushort As[BM*BK];
  __shared__ __align__(16) ushort Bs[BN*BK];
  int z=blockIdx.z, b=z/nG, g=z%nG;
  A  += (size_t)b*sAb + (size_t)g*sAg;
  Bp += (size_t)b*sBb + (size_t)g*sBg;
  size_t cOff = (size_t)b*sCb + (size_t)g*sCg;
  size_t tOff = (size_t)b*sTb + (size_t)g*sTg;
  int m0 = blockIdx.y*BM, n0 = blockIdx.x*BN;
  int tid=threadIdx.x, w=tid>>6, lane=tid&63;
  int la=lane&15, hi=lane>>4;
  int wr=w/WC, wc=w%WC;
  f32x4 acc[4][4] = {};
  constexpr int ISS = (BM+BN)*BK/2048;
  for(int k0=0;k0<K;k0+=BK){
    #pragma unroll
    for(int r=0;r<ISS;++r){
      int e = (r*256 + tid)*8;
      if(e < BM*BK){
        int row=e/BK, kk=e%BK;
        async16((char*)As + (size_t)e*2, A + (size_t)(m0+row)*lda + k0+kk);
      } else {
        int e2=e-BM*BK; int row=e2/BK, kk=e2%BK;
        async16((char*)Bs + (size_t)e2*2, Bp + (size_t)(n0+row)*ldb + k0+kk);
      }
    }
    __syncthreads();
    #pragma unroll
    for(int h=0;h<BK/32;++h){
      short8v af[4], bf4[4];
      #pragma unroll
      for(int i2=0;i2<4;++i2) af[i2] = *(const short8v*)&As[(wr*64+i2*16+la)*BK + h*32 + hi*8];
      #pragma unroll
      for(int j2=0;j2<4;++j2) bf4[j2] = *(const short8v*)&Bs[(wc*64+j2*16+la)*BK + h*32 + hi*8];
      #pragma unroll
      for(int i2=0;i2<4;++i2)
        #pragma unroll
        for(int j2=0;j2<4;++j2)
          acc[i2][j2] = __builtin_amdgcn_mfma_f32_16x16x32_bf16(af[i2], bf4[j2], acc[i2][j2], 0,0,0);
    }
    __syncthreads();
  }
  #pragma unroll
  for(int i2=0;i2<4;++i2){
    int row0 = m0 + wr*64 + i2*16 + hi*4;
    #pragma unroll
    for(int j2=0;j2<4;++j2){
      int col = n0 + wc*64 + j2*16 + la;
      float bn = biasN ? biasN[col] : 0.f;
      float cs = (scaleCb && !colbit(colmask, col)) ? 0.f : 1.f;
      #pragma unroll
      for(int r=0;r<4;++r){
        int row = row0 + r;
        float v = acc[i2][j2][r] + bn + (biasM ? biasM[(size_t)g*biasMG + row] : 0.f);
        if(corrT){
          if(scp[(size_t)b*1024 + row]==0.f && !colbit(colmask, row))
            v += (1.f/512.f)*bf2f(corrT[(size_t)b*sQb + (size_t)row*ldq + col]);
        }
        if(relu) v = fmaxf(v, 0.f);
        if(C)   C  [cOff + (size_t)row*ldc + col] = v;
        if(Cb)  Cb [cOff + (size_t)row*ldc + col] = f2bf(v*cs);
        if(CbT) CbT[tOff + (size_t)col*ldt + row] = f2bf(v);
      }
    }
  }
}

// ---------- LN1 (bf16 in) + bf16 residual -> bf16 out ----------
__global__ __launch_bounds__(256) void k_ln1(const ushort* __restrict__ o1mTb,
    const ushort* __restrict__ o1bT,
    const float* __restrict__ g1v, const float* __restrict__ be1, ushort* __restrict__ o1pb)
{
  int row=blockIdx.x, t=threadIdx.x;
  ushort2 vv = ((const ushort2*)(o1mTb + (size_t)row*MID_))[t];
  float vx=bf2f(vv.x), vy=bf2f(vv.y);
  float s=vx+vy, s2=vx*vx+vy*vy;
  for(int off=32; off; off>>=1){ s+=__shfl_down(s,off); s2+=__shfl_down(s2,off); }
  __shared__ float sm[8];
  int lane=t&63, wid=t>>6;
  if(lane==0){ sm[wid]=s; sm[4+wid]=s2; }
  __syncthreads();
  s=sm[0]+sm[1]+sm[2]+sm[3]; s2=sm[4]+sm[5]+sm[6]+sm[7];
  float mean=s*(1.f/MID_), var=s2*(1.f/MID_)-mean*mean;
  float rstd=rsqrtf(var+1e-6f);
  int m0=2*t;
  float a0=(vx-mean)*rstd*g1v[m0]+be1[m0];
  float a1=(vy-mean)*rstd*g1v[m0+1]+be1[m0+1];
  ushort2 rr = ((const ushort2*)(o1bT + (size_t)row*MID_))[t];
  ushort2 o; o.x=f2bf(a0+bf2f(rr.x)); o.y=f2bf(a1+bf2f(rr.y));
  ((ushort2*)(o1pb + (size_t)row*MID_))[t] = o;
}

// ---------- LN2 (bf16 in) + final outputs ----------
__global__ __launch_bounds__(256) void k_ln2f(const ushort* __restrict__ o2mTb,
    const ushort* __restrict__ o2bT,
    const float* __restrict__ g2v, const float* __restrict__ be2,
    float* __restrict__ node, float* __restrict__ out2)
{
  int row=blockIdx.x, t=threadIdx.x;
  float v = bf2f(o2mTb[(size_t)row*OUT_ + t]);
  float s=v, s2=v*v;
  for(int off=32; off; off>>=1){ s+=__shfl_down(s,off); s2+=__shfl_down(s2,off); }
  __shared__ float sm[8];
  int lane=t&63, wid=t>>6;
  if(lane==0){ sm[wid]=s; sm[4+wid]=s2; }
  __syncthreads();
  s=sm[0]+sm[1]+sm[2]+sm[3]; s2=sm[4]+sm[5]+sm[6]+sm[7];
  float mean=s*(1.f/OUT_); float var=s2*(1.f/OUT_)-mean*mean;
  float rstd=rsqrtf(var+1e-6f);
  float nf=(v-mean)*rstd*g2v[t]+be2[t];
  size_t ro=(size_t)row*OUT_+t;
  node[ro]=nf;
  out2[ro]=nf + bf2f(o2bT[ro]);
}

extern "C" void kernel_launch(void* const* d_in, const int* in_sizes, int n_in,
                              void* d_out, int out_size, void* d_ws, size_t ws_size,
                              hipStream_t stream)
{
  const float* x    = (const float*)d_in[0];
  const float* m1   = (const float*)d_in[1];
  const float* m2   = (const float*)d_in[2];
  const float* sc   = (const float*)d_in[3];
  const float* gt   = (const float*)d_in[4];
  const float* Watt = (const float*)d_in[5];
  const float* batt = (const float*)d_in[6];
  const float* W1   = (const float*)d_in[7];
  const float* b1   = (const float*)d_in[8];
  const float* W2   = (const float*)d_in[9];
  const float* b2   = (const float*)d_in[10];
  const float* g1   = (const float*)d_in[11];
  const float* be1  = (const float*)d_in[12];
  const float* g2   = (const float*)d_in[13];
  const float* be2  = (const float*)d_in[14];
  const float* Wg   = (const float*)d_in[15];
  const float* bg   = (const float*)d_in[16];

  float* out2 = (float*)d_out;
  float* gtso = out2 + (size_t)B_*N_*OUT_;
  float* node = gtso + (size_t)B_*N_*OUT_;

  char* ws = (char*)d_ws;
  float* lj   = (float*)(ws);                  // 64 KB
  float* li   = (float*)(ws + 65536);          // 64 KB
  ushort* W1b = (ushort*)(ws + 131072);        // 64 KB
  ushort* W2b = (ushort*)(ws + 196608);        // 64 KB
  ushort* WgTb= (ushort*)(ws + 262144);        // 128 KB
  ull* colmask= (ull*)(ws + 393216);           // 128 B
  ull* blockmask = (ull*)(ws + 1048576);       // 2 MB
  ushort* Atb = (ushort*)(ws + 4194304);       // 32 MB
  // D (16 MB): xb(8) + gtb(8) -> o2b(8) + o2bT(8)
  ushort* xb   = (ushort*)(ws + 37748736);
  ushort* gtb  = (ushort*)(ws + 46137344);
  ushort* o2b  = xb;
  ushort* o2bT = gtb;
  // E (16 MB): o1b -> o1pb
  ushort* o1b  = (ushort*)(ws + 54525952);
  ushort* o1pb = o1b;
  // F (16 MB): o1bT -> o2mTb
  ushort* o1bT = (ushort*)(ws + 71303168);
  ushort* o2mTb= (ushort*)(ws + 71303168);
  // G (16 MB): o1mTb
  ushort* o1mTb= (ushort*)(ws + 88080384);

  k_pc    <<<dim3(8192),dim3(256),0,stream>>>(x, gt, Watt, lj, li, xb, gtb);
  k_wcast <<<dim3(512),dim3(256),0,stream>>>(W1, W2, Wg, W1b, W2b, WgTb);
  k_colat <<<dim3(B_*N_),dim3(256),0,stream>>>(m1,m2,sc,lj,li,batt,Atb,blockmask);
  k_colred<<<dim3(16),dim3(256),0,stream>>>(blockmask, colmask);

  // gts = relu(gt @ Wg + bg): f32 out, no col
  mgemm<128,128,2,2,64><<<dim3(2,128,1),256,0,stream>>>(
      gtb, CIN_, 0,0,
      WgTb, CIN_, 0,0,
      gtso, (ushort*)0, OUT_, 0,0,
      (ushort*)0, 0,0,0,
      (ull*)0, 0, (ushort*)0, 0,0, (float*)0,
      CIN_, 1, nullptr,0, bg, 1);

  // gconv1: o1b[b,m,n]=relu(W1g.x)*col[n] ; o1bT[b,n,m]=relu (unscaled)
  mgemm<128,128,2,2,64><<<dim3(8,1,B_*4),256,0,stream>>>(
      W1b, 64, 0, (long long)128*64,
      xb, CIN_, (long long)N_*CIN_, 64,
      (float*)0, o1b, N_, (long long)MID_*N_, (long long)128*N_,
      o1bT, (long long)N_*MID_, 128, MID_,
      colmask, 1, (ushort*)0, 0,0, (float*)0,
      64, 4, b1, 128, nullptr, 1);

  // GEMM1: o1mTb[b,i,m] = sum_j At0[b,i,j]*o1c[b,m,j]  (+ diag correction)
  mgemm<128,128,2,2,64><<<dim3(4,8,B_),256,0,stream>>>(
      Atb, N_, (long long)N_*N_, 0,
      o1b, N_, (long long)MID_*N_, 0,
      (float*)0, o1mTb, MID_, (long long)N_*MID_, 0,
      (ushort*)0, 0,0,0,
      colmask, 0, o1bT, (long long)N_*MID_, MID_, sc,
      N_, 1, nullptr,0, nullptr, 0);

  k_ln1<<<dim3(B_*N_),256,0,stream>>>(o1mTb, o1bT, g1, be1, o1pb);

  // gconv2: o2b[b,m,n]=relu(W2g.o1p)*col[n] ; o2bT unscaled
  mgemm<64,256,1,4,64><<<dim3(4,1,B_*4),256,0,stream>>>(
      W2b, 128, 0, (long long)64*128,
      o1pb, MID_, (long long)N_*MID_, 128,
      (float*)0, o2b, N_, (long long)OUT_*N_, (long long)64*N_,
      o2bT, (long long)N_*OUT_, 64, OUT_,
      colmask, 1, (ushort*)0, 0,0, (float*)0,
      128, 4, b2, 64, nullptr, 1);

  // GEMM2: o2mTb[b,i,m] = sum_j At0[b,i,j]*o2c[b,m,j]  (+ diag correction)
  mgemm<128,128,2,2,64><<<dim3(2,8,B_),256,0,stream>>>(
      Atb, N_, (long long)N_*N_, 0,
      o2b, N_, (long long)OUT_*N_, 0,
      (float*)0, o2mTb, OUT_, (long long)N_*OUT_, 0,
      (ushort*)0, 0,0,0,
      colmask, 0, o2bT, (long long)N_*OUT_, OUT_, sc,
      N_, 1, nullptr,0, nullptr, 0);

  k_ln2f<<<dim3(B_*N_),256,0,stream>>>(o2mTb, o2bT, g2, be2, node, out2);
}

// Round 8
// 381.198 us; speedup vs baseline: 1.1162x; 1.1162x over previous
//
#include <hip/hip_runtime.h>
#include <cstddef>
#include <cstdint>

#define B_ 16
#define N_ 1024
#define CIN_ 256
#define MID_ 512
#define OUT_ 256

typedef __attribute__((ext_vector_type(8))) short short8v;
typedef __attribute__((ext_vector_type(4))) float f32x4;
typedef unsigned long long ull;

// fast sigmoid: v_exp_f32 (2^x) + v_rcp_f32; plenty accurate for bf16 outputs
__device__ __forceinline__ float sigf(float z){
  float e = __builtin_amdgcn_exp2f(-z*1.44269504f);
  return __builtin_amdgcn_rcpf(1.f+e);
}
__device__ __forceinline__ ushort f2bf(float f){
  uint32_t u=__float_as_uint(f);
  uint32_t r=(u + 0x7fffu + ((u>>16)&1u))>>16;
  return (ushort)r;
}
__device__ __forceinline__ float bf2f(ushort u){ return __uint_as_float(((uint32_t)u)<<16); }

__device__ __forceinline__ void async16(void* lds, const void* g){
  __builtin_amdgcn_global_load_lds(
      (const __attribute__((address_space(1))) uint32_t*)g,
      (__attribute__((address_space(3))) uint32_t*)lds,
      16, 0, 0);
}

// col bit for column j (word index = ((j>>8)<<2)|(j&3), bit = (j>>2)&63)
__device__ __forceinline__ int colbit(const ull* __restrict__ cm, int j){
  return (int)((cm[((j>>8)<<2) | (j&3)] >> ((j>>2)&63)) & 1ull);
}

// ---------- fused: lj/li dot products + bf16 casts of x and gt ----------
__global__ __launch_bounds__(256) void k_pc(const float* __restrict__ x,
    const float* __restrict__ gt, const float* __restrict__ Watt,
    float* __restrict__ lj, float* __restrict__ li,
    ushort* __restrict__ xb, ushort* __restrict__ gtb)
{
  int bid=blockIdx.x, wid=threadIdx.x>>6, lane=threadIdx.x&63;
  if(bid < 4096){
    int row = bid*4 + wid;
    float4 xv = ((const float4*)(x + (size_t)row*CIN_))[lane];
    ((ushort4*)(xb + (size_t)row*CIN_))[lane] =
        make_ushort4(f2bf(xv.x), f2bf(xv.y), f2bf(xv.z), f2bf(xv.w));
    float4 q = ((const float4*)Watt)[lane];
    float4 w = ((const float4*)(Watt + CIN_))[lane];
    float aq = xv.x*q.x+xv.y*q.y+xv.z*q.z+xv.w*q.w;
    float ak = xv.x*w.x+xv.y*w.y+xv.z*w.z+xv.w*w.w;
    #pragma unroll
    for(int off=32; off; off>>=1){ aq += __shfl_xor(aq,off); ak += __shfl_xor(ak,off); }
    if(lane==0){ lj[row]=aq; li[row]=ak; }
  } else {
    int row = (bid-4096)*4 + wid;
    float4 v = ((const float4*)(gt + (size_t)row*CIN_))[lane];
    ((ushort4*)(gtb + (size_t)row*CIN_))[lane] =
        make_ushort4(f2bf(v.x), f2bf(v.y), f2bf(v.z), f2bf(v.w));
  }
}

// ---------- fused weight prep: W1b, W2b, WgTb ----------
__global__ __launch_bounds__(256) void k_wcast(const float* __restrict__ W1,
    const float* __restrict__ W2, const float* __restrict__ Wg,
    ushort* __restrict__ W1b, ushort* __restrict__ W2b, ushort* __restrict__ WgTb)
{
  int bid=blockIdx.x, t=threadIdx.x;
  if(bid<128){ int i=bid*256+t; W1b[i]=f2bf(W1[i]); }
  else if(bid<256){ int i=(bid-128)*256+t; W2b[i]=f2bf(W2[i]); }
  else { int idx=(bid-256)*256+t; int o=idx>>8, c=idx&255; WgTb[idx]=f2bf(Wg[(size_t)c*OUT_+o]); }
}

// ---------- fused: At0 (no col) + per-row membership bitmask ----------
__global__ __launch_bounds__(256) void k_colat(
    const float* __restrict__ m1, const float* __restrict__ m2,
    const float* __restrict__ sc, const float* __restrict__ lj,
    const float* __restrict__ li, const float* __restrict__ batt,
    ushort* __restrict__ Atb, ull* __restrict__ blockmask)
{
  int row = blockIdx.x; int b = row >> 10; int i = row & 1023;
  int t = threadIdx.x, lane = t&63, wid = t>>6;
  size_t base = (size_t)row*N_ + 4*t;
  float4 m1v = *(const float4*)(m1 + base);
  float4 m2v = *(const float4*)(m2 + base);
  float4 scv = *(const float4*)(sc + (b<<10) + 4*t);
  float4 ljv = *(const float4*)(lj + (b<<10) + 4*t);
  float lir = li[row], ba = batt[0];
  float fi = (sc[(b<<10)+i]==0.f)?1.f:0.f;
  float mr1[4] = {m1v.x*scv.x, m1v.y*scv.y, m1v.z*scv.z, m1v.w*scv.w};
  float mr2[4] = {m2v.x*scv.x, m2v.y*scv.y, m2v.z*scv.z, m2v.w*scv.w};
  float ljr[4] = {ljv.x,ljv.y,ljv.z,ljv.w};
  ushort o[4];
  #pragma unroll
  for(int k=0;k<4;++k){
    float v = sigf(ljr[k]+lir+ba);
    float val = v*(mr1[k]+mr2[k]);
    if(4*t+k==i) val += fi;
    o[k] = f2bf(val*(1.f/512.f));
  }
  *(ushort4*)(Atb+base) = make_ushort4(o[0],o[1],o[2],o[3]);
  ull zb1m0=__ballot(mr1[0]==0.f), zb1m1=__ballot(mr1[1]==0.f),
      zb1m2=__ballot(mr1[2]==0.f), zb1m3=__ballot(mr1[3]==0.f);
  ull zb2m0=__ballot(mr2[0]==0.f), zb2m1=__ballot(mr2[1]==0.f),
      zb2m2=__ballot(mr2[2]==0.f), zb2m3=__ballot(mr2[3]==0.f);
  int wz1 = __popcll(zb1m0)+__popcll(zb1m1)+__popcll(zb1m2)+__popcll(zb1m3);
  int wz2 = __popcll(zb2m0)+__popcll(zb2m1)+__popcll(zb2m2)+__popcll(zb2m3);
  __shared__ int wz[8];
  if(lane==0){ wz[wid]=wz1; wz[4+wid]=wz2; }
  __syncthreads();
  int pre1=0, pre2=0, Z1=0, Z2=0;
  #pragma unroll
  for(int w2=0;w2<4;++w2){
    Z1 += wz[w2]; Z2 += wz[4+w2];
    if(w2<wid){ pre1 += wz[w2]; pre2 += wz[4+w2]; }
  }
  ull lt = (1ull<<lane)-1ull;
  int r1 = pre1 + __popcll(zb1m0&lt)+__popcll(zb1m1&lt)+__popcll(zb1m2&lt)+__popcll(zb1m3&lt);
  int r2 = pre2 + __popcll(zb2m0&lt)+__popcll(zb2m1&lt)+__popcll(zb2m2&lt)+__popcll(zb2m3&lt);
  int P1 = 1024-Z1, P2 = 1024-Z2;
  bool rare = (P1>128)||(P2>256)||(Z1<128)||(Z2<128);
  bool q0,q1,q2,q3;
  if(!rare){
    int zb1=r1, zb2=r2;
    q0 = (mr1[0]!=0.f)||(zb1<128)||(mr2[0]!=0.f)||(zb2<128)||(P2+zb2<256);
    zb1 += (int)((zb1m0>>lane)&1ull); zb2 += (int)((zb2m0>>lane)&1ull);
    q1 = (mr1[1]!=0.f)||(zb1<128)||(mr2[1]!=0.f)||(zb2<128)||(P2+zb2<256);
    zb1 += (int)((zb1m1>>lane)&1ull); zb2 += (int)((zb2m1>>lane)&1ull);
    q2 = (mr1[2]!=0.f)||(zb1<128)||(mr2[2]!=0.f)||(zb2<128)||(P2+zb2<256);
    zb1 += (int)((zb1m2>>lane)&1ull); zb2 += (int)((zb2m2>>lane)&1ull);
    q3 = (mr1[3]!=0.f)||(zb1<128)||(mr2[3]!=0.f)||(zb2<128)||(P2+zb2<256);
  } else {
    const float* m1r = m1 + (size_t)row*N_;
    const float* m2r = m2 + (size_t)row*N_;
    const float* scr = sc + (b<<10);
    const float* ljp = lj + (b<<10);
    float a1v[4], a2v[4];
    #pragma unroll
    for(int k=0;k<4;++k){
      float v = sigf(ljp[4*t+k]+lir+ba);
      a1v[k]=mr1[k]*v; a2v[k]=mr2[k]*v;
    }
    int c1[4]={0,0,0,0}, c1m[4]={0,0,0,0}, c2[4]={0,0,0,0}, c2m[4]={0,0,0,0};
    for(int jp=0;jp<N_;++jp){
      float vv = sigf(ljp[jp]+lir+ba);
      float p1 = m1r[jp]*scr[jp]*vv, p2 = m2r[jp]*scr[jp]*vv;
      #pragma unroll
      for(int k=0;k<4;++k){
        bool lo = jp < 4*t+k;
        c1[k] += (p1>a1v[k])||((p1==a1v[k])&&lo);
        c1m[k]+= (p1<a1v[k])||((p1==a1v[k])&&lo);
        c2[k] += (p2>a2v[k])||((p2==a2v[k])&&lo);
        c2m[k]+= (p2<a2v[k])||((p2==a2v[k])&&lo);
      }
    }
    q0 = (c1[0]<128||c1m[0]<128||c2[0]<256||c2m[0]<128);
    q1 = (c1[1]<128||c1m[1]<128||c2[1]<256||c2m[1]<128);
    q2 = (c1[2]<128||c1m[2]<128||c2[2]<256||c2m[2]<128);
    q3 = (c1[3]<128||c1m[3]<128||c2[3]<256||c2m[3]<128);
  }
  ull bq0=__ballot(q0), bq1=__ballot(q1), bq2=__ballot(q2), bq3=__ballot(q3);
  if(lane<4){
    ull v = (lane==0)?bq0 : (lane==1)?bq1 : (lane==2)?bq2 : bq3;
    blockmask[(size_t)(wid*4+lane)*16384 + row] = v;
  }
}

// ---------- OR-reduce blockmask -> colmask64 (16 words) ----------
__global__ __launch_bounds__(256) void k_colred(const ull* __restrict__ blockmask,
    ull* __restrict__ colmask64)
{
  int w = blockIdx.x;
  const ull* p = blockmask + (size_t)w*16384;
  ull acc = 0;
  for(int r=threadIdx.x; r<16384; r+=256) acc |= p[r];
  #pragma unroll
  for(int off=32; off; off>>=1) acc |= __shfl_xor(acc, off);
  __shared__ ull sm[4];
  int lane=threadIdx.x&63, wid=threadIdx.x>>6;
  if(lane==0) sm[wid]=acc;
  __syncthreads();
  if(threadIdx.x==0) colmask64[w] = sm[0]|sm[1]|sm[2]|sm[3];
}

// ---------- expand colmask -> colscale[1024] (f32) and fcorr[b][1024] ----------
__global__ __launch_bounds__(256) void k_fcorr(const ull* __restrict__ colmask,
    const float* __restrict__ sc, float* __restrict__ fcorr, float* __restrict__ colscale)
{
  int i = blockIdx.x*256 + threadIdx.x;    // 0..16383
  int j = i & 1023;
  int cb = colbit(colmask, j);
  fcorr[i] = (sc[i]==0.f && !cb) ? (1.f/512.f) : 0.f;
  if(i < 1024) colscale[i] = cb ? 1.f : 0.f;
}

// ---------- bf16 MFMA NT GEMM: C[i][m]=sum_k A[i][k]*B[m][k] ----------
// Cb: bf16 out (col-scaled by colscale if given); CbT (TRT=1): transposed bf16 copy via LDS;
// fcorr/corrT: v += fcorr[b][row]*corrT[b][row][col]
template<int BM,int BN,int WR,int WC,int BK,int TRT>
__global__ __launch_bounds__(256) void mgemm(
    const ushort* __restrict__ A, int lda, long long sAb, long long sAg,
    const ushort* __restrict__ Bp, int ldb, long long sBb, long long sBg,
    float* __restrict__ C, ushort* __restrict__ Cb, int ldc, long long sCb, long long sCg,
    ushort* __restrict__ CbT, long long sTb, long long sTg, int ldtg,
    const float* __restrict__ colscale,
    const float* __restrict__ fcorr,
    const ushort* __restrict__ corrT, long long sQb, int ldq,
    int K, int nG,
    const float* __restrict__ biasM, int biasMG,
    const float* __restrict__ biasN, int relu)
{
  static_assert(WR*WC==4 && BM==WR*64 && BN==WC*64, "tile");
  constexpr int STG = (BM+BN)*BK;          // ushorts
  constexpr int LDT = BM + 8;              // transpose LDS stride (16B-aligned cols)
  constexpr int SH  = (TRT && (BN*LDT) > STG) ? (BN*LDT) : STG;
  __shared__ __align__(16) ushort Sh[SH];
  ushort* As = Sh;
  ushort* Bs = Sh + BM*BK;
  int z=blockIdx.z, b=z/nG, g=z%nG;
  A  += (size_t)b*sAb + (size_t)g*sAg;
  Bp += (size_t)b*sBb + (size_t)g*sBg;
  size_t cOff = (size_t)b*sCb + (size_t)g*sCg;
  size_t tOff = (size_t)b*sTb + (size_t)g*sTg;
  int m0 = blockIdx.y*BM, n0 = blockIdx.x*BN;
  int tid=threadIdx.x, w=tid>>6, lane=tid&63;
  int la=lane&15, hi=lane>>4;
  int wr=w/WC, wc=w%WC;
  f32x4 acc[4][4] = {};
  constexpr int ISS = (BM+BN)*BK/2048;
  for(int k0=0;k0<K;k0+=BK){
    #pragma unroll
    for(int r=0;r<ISS;++r){
      int e = (r*256 + tid)*8;
      if(e < BM*BK){
        int row=e/BK, kk=e%BK;
        async16((char*)As + (size_t)e*2, A + (size_t)(m0+row)*lda + k0+kk);
      } else {
        int e2=e-BM*BK; int row=e2/BK, kk=e2%BK;
        async16((char*)Bs + (size_t)e2*2, Bp + (size_t)(n0+row)*ldb + k0+kk);
      }
    }
    __syncthreads();
    #pragma unroll
    for(int h=0;h<BK/32;++h){
      short8v af[4], bf4[4];
      #pragma unroll
      for(int i2=0;i2<4;++i2) af[i2] = *(const short8v*)&As[(wr*64+i2*16+la)*BK + h*32 + hi*8];
      #pragma unroll
      for(int j2=0;j2<4;++j2) bf4[j2] = *(const short8v*)&Bs[(wc*64+j2*16+la)*BK + h*32 + hi*8];
      #pragma unroll
      for(int i2=0;i2<4;++i2)
        #pragma unroll
        for(int j2=0;j2<4;++j2)
          acc[i2][j2] = __builtin_amdgcn_mfma_f32_16x16x32_bf16(af[i2], bf4[j2], acc[i2][j2], 0,0,0);
    }
    __syncthreads();
  }
  // ---- epilogue: hoisted per-col / per-row scalars ----
  int colL[4]; float bnv[4], csv[4];
  #pragma unroll
  for(int j2=0;j2<4;++j2){
    colL[j2] = wc*64 + j2*16 + la;
    int col = n0 + colL[j2];
    bnv[j2] = biasN ? biasN[col] : 0.f;
    csv[j2] = colscale ? colscale[col] : 1.f;
  }
  #pragma unroll
  for(int i2=0;i2<4;++i2){
    int rowB = wr*64 + i2*16 + hi*4;
    float bmv[4], fcv[4];
    #pragma unroll
    for(int r=0;r<4;++r){
      int row = m0 + rowB + r;
      bmv[r] = biasM ? biasM[(size_t)g*biasMG + row] : 0.f;
      fcv[r] = fcorr ? fcorr[(size_t)b*1024 + row] : 0.f;
    }
    #pragma unroll
    for(int j2=0;j2<4;++j2){
      int col = n0 + colL[j2];
      ushort pk[4];
      #pragma unroll
      for(int r=0;r<4;++r){
        int row = m0 + rowB + r;
        float v = acc[i2][j2][r] + bnv[j2] + bmv[r];
        if(corrT && fcv[r]!=0.f)
          v += fcv[r]*bf2f(corrT[(size_t)b*sQb + (size_t)row*ldq + col]);
        if(relu) v = fmaxf(v,0.f);
        if(C)  C [cOff + (size_t)row*ldc + col] = v;
        if(Cb) Cb[cOff + (size_t)row*ldc + col] = f2bf(v*csv[j2]);
        if(TRT) pk[r] = f2bf(v);
      }
      if(TRT) *(ushort4*)&Sh[(size_t)colL[j2]*LDT + rowB] = make_ushort4(pk[0],pk[1],pk[2],pk[3]);
    }
  }
  if(TRT){
    __syncthreads();
    #pragma unroll
    for(int u=0;u<BM*BN/2048;++u){
      int idx = u*256 + tid;
      int col = idx/(BM/8), r8 = idx%(BM/8);
      short8v vv = *(const short8v*)&Sh[(size_t)col*LDT + r8*8];
      *(short8v*)(CbT + tOff + (size_t)(n0+col)*ldtg + m0 + r8*8) = vv;
    }
  }
}

// ---------- LN1 (bf16 in) + bf16 residual -> bf16 out ----------
__global__ __launch_bounds__(256) void k_ln1(const ushort* __restrict__ o1mTb,
    const ushort* __restrict__ o1bT,
    const float* __restrict__ g1v, const float* __restrict__ be1, ushort* __restrict__ o1pb)
{
  int row=blockIdx.x, t=threadIdx.x;
  ushort2 vv = ((const ushort2*)(o1mTb + (size_t)row*MID_))[t];
  float vx=bf2f(vv.x), vy=bf2f(vv.y);
  float s=vx+vy, s2=vx*vx+vy*vy;
  for(int off=32; off; off>>=1){ s+=__shfl_down(s,off); s2+=__shfl_down(s2,off); }
  __shared__ float sm[8];
  int lane=t&63, wid=t>>6;
  if(lane==0){ sm[wid]=s; sm[4+wid]=s2; }
  __syncthreads();
  s=sm[0]+sm[1]+sm[2]+sm[3]; s2=sm[4]+sm[5]+sm[6]+sm[7];
  float mean=s*(1.f/MID_), var=s2*(1.f/MID_)-mean*mean;
  float rstd=rsqrtf(var+1e-6f);
  int m0=2*t;
  float a0=(vx-mean)*rstd*g1v[m0]+be1[m0];
  float a1=(vy-mean)*rstd*g1v[m0+1]+be1[m0+1];
  ushort2 rr = ((const ushort2*)(o1bT + (size_t)row*MID_))[t];
  ushort2 o; o.x=f2bf(a0+bf2f(rr.x)); o.y=f2bf(a1+bf2f(rr.y));
  ((ushort2*)(o1pb + (size_t)row*MID_))[t] = o;
}

// ---------- LN2 (bf16 in) + final outputs ----------
__global__ __launch_bounds__(256) void k_ln2f(const ushort* __restrict__ o2mTb,
    const ushort* __restrict__ o2bT,
    const float* __restrict__ g2v, const float* __restrict__ be2,
    float* __restrict__ node, float* __restrict__ out2)
{
  int row=blockIdx.x, t=threadIdx.x;
  float v = bf2f(o2mTb[(size_t)row*OUT_ + t]);
  float s=v, s2=v*v;
  for(int off=32; off; off>>=1){ s+=__shfl_down(s,off); s2+=__shfl_down(s2,off); }
  __shared__ float sm[8];
  int lane=t&63, wid=t>>6;
  if(lane==0){ sm[wid]=s; sm[4+wid]=s2; }
  __syncthreads();
  s=sm[0]+sm[1]+sm[2]+sm[3]; s2=sm[4]+sm[5]+sm[6]+sm[7];
  float mean=s*(1.f/OUT_); float var=s2*(1.f/OUT_)-mean*mean;
  float rstd=rsqrtf(var+1e-6f);
  float nf=(v-mean)*rstd*g2v[t]+be2[t];
  size_t ro=(size_t)row*OUT_+t;
  node[ro]=nf;
  out2[ro]=nf + bf2f(o2bT[ro]);
}

extern "C" void kernel_launch(void* const* d_in, const int* in_sizes, int n_in,
                              void* d_out, int out_size, void* d_ws, size_t ws_size,
                              hipStream_t stream)
{
  const float* x    = (const float*)d_in[0];
  const float* m1   = (const float*)d_in[1];
  const float* m2   = (const float*)d_in[2];
  const float* sc   = (const float*)d_in[3];
  const float* gt   = (const float*)d_in[4];
  const float* Watt = (const float*)d_in[5];
  const float* batt = (const float*)d_in[6];
  const float* W1   = (const float*)d_in[7];
  const float* b1   = (const float*)d_in[8];
  const float* W2   = (const float*)d_in[9];
  const float* b2   = (const float*)d_in[10];
  const float* g1   = (const float*)d_in[11];
  const float* be1  = (const float*)d_in[12];
  const float* g2   = (const float*)d_in[13];
  const float* be2  = (const float*)d_in[14];
  const float* Wg   = (const float*)d_in[15];
  const float* bg   = (const float*)d_in[16];

  float* out2 = (float*)d_out;
  float* gtso = out2 + (size_t)B_*N_*OUT_;
  float* node = gtso + (size_t)B_*N_*OUT_;

  char* ws = (char*)d_ws;
  float* lj    = (float*)(ws);                 // 64 KB
  float* li    = (float*)(ws + 65536);         // 64 KB
  ushort* W1b  = (ushort*)(ws + 131072);       // 64 KB
  ushort* W2b  = (ushort*)(ws + 196608);       // 64 KB
  ushort* WgTb = (ushort*)(ws + 262144);       // 128 KB
  ull* colmask = (ull*)(ws + 393216);          // 128 B
  float* colscale = (float*)(ws + 397312);     // 4 KB
  float* fcorr = (float*)(ws + 401408);        // 64 KB
  ull* blockmask = (ull*)(ws + 1048576);       // 2 MB
  ushort* Atb  = (ushort*)(ws + 4194304);      // 32 MB
  // D (16 MB): xb(8) + gtb(8) -> o2b(8) + o2bT(8)
  ushort* xb   = (ushort*)(ws + 37748736);
  ushort* gtb  = (ushort*)(ws + 46137344);
  ushort* o2b  = xb;
  ushort* o2bT = gtb;
  // E (16 MB): o1b -> o1pb
  ushort* o1b  = (ushort*)(ws + 54525952);
  ushort* o1pb = o1b;
  // F (16 MB): o1bT -> o2mTb
  ushort* o1bT = (ushort*)(ws + 71303168);
  ushort* o2mTb= (ushort*)(ws + 71303168);
  // G (16 MB): o1mTb
  ushort* o1mTb= (ushort*)(ws + 88080384);

  k_pc    <<<dim3(8192),dim3(256),0,stream>>>(x, gt, Watt, lj, li, xb, gtb);
  k_wcast <<<dim3(512),dim3(256),0,stream>>>(W1, W2, Wg, W1b, W2b, WgTb);
  k_colat <<<dim3(B_*N_),dim3(256),0,stream>>>(m1,m2,sc,lj,li,batt,Atb,blockmask);
  k_colred<<<dim3(16),dim3(256),0,stream>>>(blockmask, colmask);
  k_fcorr <<<dim3(64),dim3(256),0,stream>>>(colmask, sc, fcorr, colscale);

  // gts = relu(gt @ Wg + bg): f32 out
  mgemm<128,128,2,2,64,0><<<dim3(2,128,1),256,0,stream>>>(
      gtb, CIN_, 0,0,
      WgTb, CIN_, 0,0,
      gtso, (ushort*)0, OUT_, 0,0,
      (ushort*)0, 0,0,0,
      nullptr, nullptr, (ushort*)0, 0,0,
      CIN_, 1, nullptr,0, bg, 1);

  // gconv1: o1b[b,m,n]=relu(W1g.x)*col[n] ; o1bT[b,n,m]=relu (unscaled, LDS transpose)
  mgemm<128,128,2,2,64,1><<<dim3(8,1,B_*4),256,0,stream>>>(
      W1b, 64, 0, (long long)128*64,
      xb, CIN_, (long long)N_*CIN_, 64,
      (float*)0, o1b, N_, (long long)MID_*N_, (long long)128*N_,
      o1bT, (long long)N_*MID_, 128, MID_,
      colscale, nullptr, (ushort*)0, 0,0,
      64, 4, b1, 128, nullptr, 1);

  // GEMM1: o1mTb[b,i,m] = sum_j At0[b,i,j]*o1c[b,m,j] (+ fcorr diag correction)
  mgemm<128,128,2,2,64,0><<<dim3(4,8,B_),256,0,stream>>>(
      Atb, N_, (long long)N_*N_, 0,
      o1b, N_, (long long)MID_*N_, 0,
      (float*)0, o1mTb, MID_, (long long)N_*MID_, 0,
      (ushort*)0, 0,0,0,
      nullptr, fcorr, o1bT, (long long)N_*MID_, MID_,
      N_, 1, nullptr,0, nullptr, 0);

  k_ln1<<<dim3(B_*N_),256,0,stream>>>(o1mTb, o1bT, g1, be1, o1pb);

  // gconv2: o2b[b,m,n]=relu(W2g.o1p)*col[n] ; o2bT unscaled (LDS transpose)
  mgemm<64,256,1,4,64,1><<<dim3(4,1,B_*4),256,0,stream>>>(
      W2b, 128, 0, (long long)64*128,
      o1pb, MID_, (long long)N_*MID_, 128,
      (float*)0, o2b, N_, (long long)OUT_*N_, (long long)64*N_,
      o2bT, (long long)N_*OUT_, 64, OUT_,
      colscale, nullptr, (ushort*)0, 0,0,
      128, 4, b2, 64, nullptr, 1);

  // GEMM2: o2mTb[b,i,m] = sum_j At0[b,i,j]*o2c[b,m,j] (+ fcorr diag correction)
  mgemm<128,128,2,2,64,0><<<dim3(2,8,B_),256,0,stream>>>(
      Atb, N_, (long long)N_*N_, 0,
      o2b, N_, (long long)OUT_*N_, 0,
      (float*)0, o2mTb, OUT_, (long long)N_*OUT_, 0,
      (ushort*)0, 0,0,0,
      nullptr, fcorr, o2bT, (long long)N_*OUT_, OUT_,
      N_, 1, nullptr,0, nullptr, 0);

  k_ln2f<<<dim3(B_*N_),256,0,stream>>>(o2mTb, o2bT, g2, be2, node, out2);
}